// Round 6
// baseline (130.868 us; speedup 1.0000x reference)
//
#include <hip/hip_runtime.h>
#include <hip/hip_bf16.h>
#include <math.h>

#define BB 32
#define SS 1024
#define DH 512      // DEC_HID
#define EH2 1024    // 2*ENC_HID
#define WROW 1536   // in_dim
#define NEGV -1.0e10f

typedef __attribute__((ext_vector_type(8))) short s16x8;
typedef __attribute__((ext_vector_type(16))) float f32x16;
typedef unsigned short u16;
typedef unsigned int u32;

// LDS row = 128 B: [hi k0..31 | lo k0..31], 8 slots of 16 B, XOR-swizzled.
__device__ __forceinline__ int swz(int row, int slot) {
    return row * 64 + ((slot ^ (row & 7)) << 3);
}

__device__ __forceinline__ void split8(const float4& v0, const float4& v1,
                                       s16x8& hi, s16x8& lo) {
    float xs[8] = {v0.x, v0.y, v0.z, v0.w, v1.x, v1.y, v1.z, v1.w};
    union { u16 u[8]; s16x8 v; } H, L;
#pragma unroll
    for (int j = 0; j < 8; ++j) {
        u32 u = __builtin_bit_cast(u32, xs[j]);
        u32 hb = u & 0xFFFF0000u;
        float rem = xs[j] - __builtin_bit_cast(float, hb);
        H.u[j] = (u16)(u >> 16);
        L.u[j] = __builtin_bit_cast(u16, __float2bfloat16(rem));
    }
    hi = H.v;
    lo = L.v;
}

__device__ __forceinline__ float fast_tanh(float x) {
    float a = fabsf(x);
    float e = __expf(2.0f * a);
    float r = 1.0f - 2.0f / (e + 1.0f);   // e->inf gives r=1, no NaN
    return copysignf(r, x);
}

// ---------------- Kernel A: h_proj[b,d] = hidden[b,:] . W[d,:512] + bias[d]
__global__ void hproj_kernel(const float* __restrict__ hidden,
                             const float* __restrict__ W,
                             const float* __restrict__ bias,
                             float* __restrict__ hproj) {
    int wave = (int)((blockIdx.x * blockDim.x + threadIdx.x) >> 6);
    int lane = threadIdx.x & 63;
    if (wave >= BB * DH) return;
    int b = wave >> 9;
    int d = wave & 511;
    const float* hrow = hidden + b * DH;
    const float* wrow = W + (size_t)d * WROW;
    float sum = 0.f;
#pragma unroll
    for (int u = 0; u < 8; ++u) {
        int k = lane + 64 * u;
        sum = fmaf(hrow[k], wrow[k], sum);
    }
#pragma unroll
    for (int off = 32; off > 0; off >>= 1)
        sum += __shfl_xor(sum, off, 64);
    if (lane == 0) hproj[wave] = sum + bias[d];
}

// ---------------- Kernel B0: pre-split We into swizzled per-(nblk,kt) tile images
__global__ void bsplit_kernel(const float* __restrict__ W,
                              u16* __restrict__ img) {
    int idx = blockIdx.x * 256 + threadIdx.x;   // 512 cols * 128 k-octets
    int c = idx >> 7;         // 0..511 (We row = output col d)
    int ko = idx & 127;       // k-octet 0..127
    int k = ko * 8;
    const float* src = W + (size_t)c * WROW + DH + k;
    float4 v0 = *(const float4*)src;
    float4 v1 = *(const float4*)(src + 4);
    s16x8 hi, lo;
    split8(v0, v1, hi, lo);
    int nb = c >> 8;          // n-block (256 cols each)
    int cp = c & 255;         // col within tile
    int kt = ko >> 2;         // K-step
    int sl = ko & 3;          // hi slot
    u16* tb = img + ((size_t)(nb * 32 + kt) << 14);   // 16384 ushorts per tile
    *(s16x8*)(tb + swz(cp, sl)) = hi;
    *(s16x8*)(tb + swz(cp, sl + 4)) = lo;
}

// ---------------- Kernel B: 8-wave 256x256 tile, 32x32x16 MFMA, 2-phase K-steps
// grid: 256 blocks (128 m x 2 n, XCD-chunked), 512 threads
__global__ __launch_bounds__(512, 2)
void energy_mfma_kernel(const float* __restrict__ enc,
                        const u16* __restrict__ bimg,
                        const float* __restrict__ hproj,
                        const float* __restrict__ v,
                        float* __restrict__ scores) {
    __shared__ u16 sA[2][256 * 64];   // 32 KB each
    __shared__ u16 sB[2][256 * 64];

    const int tid = threadIdx.x;
    const int lane = tid & 63;
    const int wid = tid >> 6;
    const int l31 = lane & 31;
    const int lh = lane >> 5;         // 0/1

    // XCD-chunked decode: 8 XCDs x 32 contiguous flat ids
    const int flat = (blockIdx.x & 7) * 32 + (blockIdx.x >> 3);
    const int nblk = flat & 1;
    const int mblk = flat >> 1;       // 0..127
    const int b = mblk >> 2;
    const int srow = (mblk & 3) * 256;
    const int d0 = nblk * 256;

    const int wm = (wid >> 2) * 128;  // wave row offset (2 M-waves)
    const int wn = (wid & 3) * 64;    // wave col offset (4 N-waves)

    const float* aBase = enc + ((size_t)(b * SS + srow)) * EH2;
    const u16* tBase = bimg + (((size_t)nblk * 32) << 14);

    const int arow = tid >> 1;        // 0..255
    const int ahalf = tid & 1;        // k 0..15 / 16..31

    f32x16 acc[4][2];
#pragma unroll
    for (int m = 0; m < 4; ++m)
#pragma unroll
        for (int n = 0; n < 2; ++n)
#pragma unroll
            for (int r = 0; r < 16; ++r) acc[m][n][r] = 0.f;

    float4 rA[4];
    auto loadA = [&](int t) {
        const float* p = aBase + (size_t)arow * EH2 + t * 32 + ahalf * 16;
        rA[0] = ((const float4*)p)[0];
        rA[1] = ((const float4*)p)[1];
        rA[2] = ((const float4*)p)[2];
        rA[3] = ((const float4*)p)[3];
    };
    auto writeA = [&](int buf) {
        s16x8 h0, l0, h1, l1;
        split8(rA[0], rA[1], h0, l0);
        split8(rA[2], rA[3], h1, l1);
        u16* base = &sA[buf][0];
        *(s16x8*)&base[swz(arow, ahalf * 2)]     = h0;
        *(s16x8*)&base[swz(arow, ahalf * 2 + 1)] = h1;
        *(s16x8*)&base[swz(arow, 4 + ahalf * 2)]     = l0;
        *(s16x8*)&base[swz(arow, 4 + ahalf * 2 + 1)] = l1;
    };
    auto stageB = [&](int t, int buf) {
        const u16* tb = tBase + ((size_t)t << 14);
#pragma unroll
        for (int q = 0; q < 4; ++q) {
            int o = (wid * 4 + q) * 512;   // ushort units, 1 KB per inst
            __builtin_amdgcn_global_load_lds(
                (const __attribute__((address_space(1))) u32*)(tb + o + lane * 8),
                (__attribute__((address_space(3))) u32*)&sB[buf][o],
                16, 0, 0);
        }
    };

    s16x8 bH[2][2], bL[2][2];     // [nt][kk]
    auto readB = [&](int buf) {
#pragma unroll
        for (int nt = 0; nt < 2; ++nt) {
            int col = wn + nt * 32 + l31;
#pragma unroll
            for (int kk = 0; kk < 2; ++kk) {
                int slot = kk * 2 + lh;
                bH[nt][kk] = *(const s16x8*)&sB[buf][swz(col, slot)];
                bL[nt][kk] = *(const s16x8*)&sB[buf][swz(col, slot + 4)];
            }
        }
    };

    s16x8 aH[2][2], aL[2][2];     // [i][kk]
    auto readA2 = [&](int buf, int half) {
#pragma unroll
        for (int i = 0; i < 2; ++i) {
            int row = wm + (half * 2 + i) * 32 + l31;
#pragma unroll
            for (int kk = 0; kk < 2; ++kk) {
                int slot = kk * 2 + lh;
                aH[i][kk] = *(const s16x8*)&sA[buf][swz(row, slot)];
                aL[i][kk] = *(const s16x8*)&sA[buf][swz(row, slot + 4)];
            }
        }
    };

    auto mfma_half = [&](int half) {
        __builtin_amdgcn_s_setprio(1);
#pragma unroll
        for (int kk = 0; kk < 2; ++kk)
#pragma unroll
            for (int i = 0; i < 2; ++i)
#pragma unroll
                for (int nt = 0; nt < 2; ++nt) {
                    int m = half * 2 + i;
                    acc[m][nt] = __builtin_amdgcn_mfma_f32_32x32x16_bf16(aH[i][kk], bH[nt][kk], acc[m][nt], 0, 0, 0);
                    acc[m][nt] = __builtin_amdgcn_mfma_f32_32x32x16_bf16(aH[i][kk], bL[nt][kk], acc[m][nt], 0, 0, 0);
                    acc[m][nt] = __builtin_amdgcn_mfma_f32_32x32x16_bf16(aL[i][kk], bH[nt][kk], acc[m][nt], 0, 0, 0);
                }
        __builtin_amdgcn_s_setprio(0);
    };

    // ---- prologue: fill buffer 0
    stageB(0, 0);
    loadA(0);
    writeA(0);   // drains prologue vmem; loop steady-state stays counted

#pragma unroll 1
    for (int t = 0; t < 31; ++t) {
        const int cur = t & 1;
        loadA(t + 1);                                   // A(t+1): 4 vmem
        asm volatile("s_waitcnt vmcnt(4) lgkmcnt(0)" ::: "memory"); // B(t) landed; A(t+1) flies
        __builtin_amdgcn_s_barrier();                   // tile [cur] valid for all waves
        __builtin_amdgcn_sched_barrier(0);
        readB(cur);                                     // 8 ds_read_b128
        readA2(cur, 0);                                 // 8 ds_read_b128
        __builtin_amdgcn_s_barrier();                   // phase 0 open
        mfma_half(0);                                   // 24 MFMA 32x32x16
        __builtin_amdgcn_s_barrier();                   // phase 0 close
        stageB(t + 1, cur ^ 1);                         // B(t+1): 4 gload_lds
        readA2(cur, 1);
        __builtin_amdgcn_s_barrier();                   // phase 1 open
        mfma_half(1);
        __builtin_amdgcn_s_barrier();                   // phase 1 close
        writeA(cur ^ 1);                                // auto vmcnt(4): waits A(t+1)
    }
    // ---- peeled last step (t = 31, buffer 1)
    asm volatile("s_waitcnt vmcnt(0) lgkmcnt(0)" ::: "memory");
    __builtin_amdgcn_s_barrier();
    __builtin_amdgcn_sched_barrier(0);
    readB(1);
    readA2(1, 0);
    __builtin_amdgcn_s_barrier();
    mfma_half(0);
    __builtin_amdgcn_s_barrier();
    readA2(1, 1);
    __builtin_amdgcn_s_barrier();
    mfma_half(1);

    // ---- epilogue: partial scores = sum_d tanh(e_proj + h_proj)*v
    float hp[2], vv[2];
#pragma unroll
    for (int nt = 0; nt < 2; ++nt) {
        int c = d0 + wn + nt * 32 + l31;
        hp[nt] = hproj[b * DH + c];
        vv[nt] = v[c];
    }
    float* srowBase = scores + b * SS + srow + wm;
#pragma unroll
    for (int mt = 0; mt < 4; ++mt)
#pragma unroll
        for (int r = 0; r < 16; ++r) {
            float p = fast_tanh(acc[mt][0][r] + hp[0]) * vv[0]
                    + fast_tanh(acc[mt][1][r] + hp[1]) * vv[1];
            p += __shfl_xor(p, 1, 64);
            p += __shfl_xor(p, 2, 64);
            p += __shfl_xor(p, 4, 64);
            p += __shfl_xor(p, 8, 64);
            p += __shfl_xor(p, 16, 64);
            if (l31 == 0)
                atomicAdd(&srowBase[mt * 32 + (r & 3) + 8 * (r >> 2) + 4 * lh], p);
        }
}

// ---------------- Kernel C: masked softmax over S per batch row
__global__ void softmax_kernel(const float* __restrict__ scores,
                               const int* __restrict__ mask,
                               float* __restrict__ out) {
    __shared__ float red[8];
    int b = blockIdx.x;
    int tid = threadIdx.x;
    int lane = tid & 63;
    int wid = tid >> 6;

    float x[4];
    float mx = -INFINITY;
#pragma unroll
    for (int u = 0; u < 4; ++u) {
        int s = tid + 256 * u;
        float sc = scores[b * SS + s];
        if (mask[b * SS + s] == 0) sc = NEGV;
        x[u] = sc;
        mx = fmaxf(mx, sc);
    }
#pragma unroll
    for (int off = 32; off > 0; off >>= 1)
        mx = fmaxf(mx, __shfl_xor(mx, off, 64));
    if (lane == 0) red[wid] = mx;
    __syncthreads();
    mx = fmaxf(fmaxf(red[0], red[1]), fmaxf(red[2], red[3]));

    float sum = 0.f;
#pragma unroll
    for (int u = 0; u < 4; ++u) {
        x[u] = expf(x[u] - mx);
        sum += x[u];
    }
#pragma unroll
    for (int off = 32; off > 0; off >>= 1)
        sum += __shfl_xor(sum, off, 64);
    __syncthreads();
    if (lane == 0) red[4 + wid] = sum;
    __syncthreads();
    sum = red[4] + red[5] + red[6] + red[7];
    float inv = 1.0f / sum;
#pragma unroll
    for (int u = 0; u < 4; ++u)
        out[b * SS + tid + 256 * u] = x[u] * inv;
}

extern "C" void kernel_launch(void* const* d_in, const int* in_sizes, int n_in,
                              void* d_out, int out_size, void* d_ws, size_t ws_size,
                              hipStream_t stream) {
    const float* hidden = (const float*)d_in[0];
    const float* enc    = (const float*)d_in[1];
    const int*   mask   = (const int*)d_in[2];
    const float* W      = (const float*)d_in[3];
    const float* bias   = (const float*)d_in[4];
    const float* v      = (const float*)d_in[5];
    float* out = (float*)d_out;

    float* hproj = (float*)d_ws;                          // 64 KB
    float* scores = (float*)((char*)d_ws + 64 * 1024);    // 128 KB
    u16* bimg = (u16*)((char*)d_ws + 192 * 1024);         // 2 MB swizzled tiles

    hipMemsetAsync(scores, 0, BB * SS * sizeof(float), stream);

    bsplit_kernel<<<256, 256, 0, stream>>>(W, bimg);
    hproj_kernel<<<BB * DH / 4, 256, 0, stream>>>(hidden, W, bias, hproj);
    energy_mfma_kernel<<<256, 512, 0, stream>>>(enc, bimg, hproj, v, scores);
    softmax_kernel<<<BB, 256, 0, stream>>>(scores, mask, out);
}